// Round 3
// baseline (122.029 us; speedup 1.0000x reference)
//
#include <hip/hip_runtime.h>

// ---------------------------------------------------------------------------
// ModernBertAttention: x[4,2048,768] -> QKV gemm(+RoPE) -> sliding-window
// MFMA attention (window=64) -> out-proj gemm.  out f32 [4,2048,768].
// ---------------------------------------------------------------------------

typedef __attribute__((ext_vector_type(8))) _Float16 f16x8;
typedef __attribute__((ext_vector_type(4))) float    f32x4;

#define BDIM 4
#define SDIM 2048
#define HDIM 768
#define NH   12
#define HD   64
#define NQKV 2304   // 3*HDIM
#define MROWS 8192  // B*S

// ---------------------------------------------------------------------------
__device__ __forceinline__ void gload16(const void* g, void* l) {
    __builtin_amdgcn_global_load_lds(
        (__attribute__((address_space(1))) void*)(g),
        (__attribute__((address_space(3))) void*)(l),
        16, 0, 0);
}

// --------------------------- f32 -> f16 convert ----------------------------
__global__ __launch_bounds__(256) void cvt_f32_f16(
    const float* __restrict__ src, _Float16* __restrict__ dst, int n8)
{
    int i = blockIdx.x * 256 + threadIdx.x;
    if (i >= n8) return;
    const float4* s4 = (const float4*)src + (long)i * 2;
    float4 a = s4[0], b = s4[1];
    f16x8 o;
    o[0] = (_Float16)a.x; o[1] = (_Float16)a.y;
    o[2] = (_Float16)a.z; o[3] = (_Float16)a.w;
    o[4] = (_Float16)b.x; o[5] = (_Float16)b.y;
    o[6] = (_Float16)b.z; o[7] = (_Float16)b.w;
    *((f16x8*)dst + i) = o;
}

// ------------------------------- GEMM --------------------------------------
// C[M,N] = A[M,K] * Bt[N,K]^T, fp16 inputs, fp32 accum.
// LDS tiles XOR-swizzled (granule g_phys = g_log ^ (row&3)):
//   - staging pre-swizzles the GLOBAL source column (global_load_lds writes
//     linearly: dest = wave base + lane*16)
//   - ds_read applies the same XOR on the column
// -> ds_read_b128 spreads 64 lanes over all 8 bank-quads: conflict-free.
// EPI==0: plain f32 C store.
// EPI==1: qkv epilogue: RoPE on q/k, scatter q/k/v (all f16) to [B,nh,S,hd].
template <int EPI>
__global__ __launch_bounds__(256) void gemm_kernel(
    const _Float16* __restrict__ A,
    const _Float16* __restrict__ Bt,
    float* __restrict__ C,
    const float* __restrict__ cosp,
    const float* __restrict__ sinp,
    _Float16* __restrict__ qh,
    _Float16* __restrict__ kh,
    _Float16* __restrict__ vh,
    int M, int N, int K)
{
    __shared__ __align__(16) _Float16 lsA[128 * 32];
    __shared__ __align__(16) _Float16 lsB[128 * 32];

    int nTn = N >> 7;
    int nwg = gridDim.x;
    int bid = blockIdx.x;
    int wg = bid;
    if ((nwg & 7) == 0) {                 // XCD-aware bijective swizzle
        int cpx = nwg >> 3;
        wg = (bid & 7) * cpx + (bid >> 3);
    }
    int tm = wg / nTn, tn = wg % nTn;
    int m0 = tm << 7, n0 = tn << 7;

    int tid  = threadIdx.x;
    int lane = tid & 63;
    int w    = tid >> 6;
    int wr   = w >> 1, wc = w & 1;
    int l15  = lane & 15, lk = lane >> 4;

    f32x4 acc[4][4] = {};

    // staging: thread tid fills LDS bytes [tid*16, tid*16+16) = row tid>>2,
    // physical granule tid&3. Source col pre-swizzled so the read-side XOR
    // finds logical granule g at physical g ^ (row&3).
    int srow = tid >> 2;
    int scol = ((tid & 3) ^ (srow & 3)) << 3;
    const _Float16* ga0 = A  + (long)(m0 + srow) * K + scol;
    const _Float16* gb0 = Bt + (long)(n0 + srow) * K + scol;
    _Float16* la = &lsA[tid * 8];
    _Float16* lb = &lsB[tid * 8];
    const long gstep = (long)64 * K;      // (srow+64)&3 == srow&3: scol reusable

    for (int k0 = 0; k0 < K; k0 += 32) {
        __syncthreads();
        gload16(ga0 + k0,         la);
        gload16(ga0 + gstep + k0, la + 2048);
        gload16(gb0 + k0,         lb);
        gload16(gb0 + gstep + k0, lb + 2048);
        __syncthreads();

        f16x8 af[4], bfr[4];
#pragma unroll
        for (int m = 0; m < 4; ++m) {
            int row = wr * 64 + m * 16 + l15;          // row&3 == l15&3
            af[m] = *(const f16x8*)&lsA[row * 32 + ((lk ^ (l15 & 3)) << 3)];
        }
#pragma unroll
        for (int n = 0; n < 4; ++n) {
            int row = wc * 64 + n * 16 + l15;
            bfr[n] = *(const f16x8*)&lsB[row * 32 + ((lk ^ (l15 & 3)) << 3)];
        }
#pragma unroll
        for (int m = 0; m < 4; ++m)
#pragma unroll
            for (int n = 0; n < 4; ++n)
                acc[m][n] = __builtin_amdgcn_mfma_f32_16x16x32_f16(
                    af[m], bfr[n], acc[m][n], 0, 0, 0);
    }

    if (EPI == 0) {
#pragma unroll
        for (int m = 0; m < 4; ++m)
#pragma unroll
            for (int n = 0; n < 4; ++n)
#pragma unroll
                for (int j = 0; j < 4; ++j) {
                    int gr = m0 + wr * 64 + m * 16 + lk * 4 + j;
                    int gc = n0 + wc * 64 + n * 16 + l15;
                    C[(long)gr * N + gc] = acc[m][n][j];
                }
    } else {
        int ht = (n0 >> 6) + wc;       // [0,36): t*12 + h
        int t  = ht / NH;
        int h  = ht - t * NH;
        int b  = m0 >> 11;
        long base_bh = ((long)(b * NH + h)) * SDIM;
#pragma unroll
        for (int m = 0; m < 4; ++m) {
#pragma unroll
            for (int j = 0; j < 4; ++j) {
                int gr = m0 + wr * 64 + m * 16 + lk * 4 + j;
                int s  = gr & (SDIM - 1);
                if (t == 2) {
#pragma unroll
                    for (int n = 0; n < 4; ++n) {
                        int d = n * 16 + l15;
                        vh[(base_bh + s) * HD + d] = (_Float16)acc[m][n][j];
                    }
                } else {
                    float vals[4];
#pragma unroll
                    for (int n = 0; n < 4; ++n) vals[n] = acc[m][n][j];
#pragma unroll
                    for (int n = 0; n < 4; ++n) {
                        int d = n * 16 + l15;
                        float cc = cosp[(long)gr * HD + d];
                        float ss = sinp[(long)gr * HD + d];
                        float pv = (n < 2) ? -vals[n + 2] : vals[n - 2];
                        float o  = vals[n] * cc + pv * ss;
                        long oidx = (base_bh + s) * HD + d;
                        if (t == 0) qh[oidx] = (_Float16)o;
                        else        kh[oidx] = (_Float16)o;
                    }
                }
            }
        }
    }
}

// ---------------------------- MFMA attention --------------------------------
// Block = 4 waves = one (b,h, 64-query tile); key window = 192 keys.
// QK^T: A=Q (direct global frags), B=K rows (direct global frags).
// exp+mask in-register; row-sums via 16-lane shfl_xor; P -> LDS f16.
// V staged once per block to LDS transposed f16; PV MFMA from LDS.
#define SSTR 200   // lsVT row stride (f16): 400B, 16B-aligned, conflict-benign
#define PSTR 200   // lsP  row stride (f16)
__global__ __launch_bounds__(256) void attn_mfma(
    const _Float16* __restrict__ qh,
    const _Float16* __restrict__ kh,
    const _Float16* __restrict__ vh,
    _Float16* __restrict__ yh)
{
    __shared__ __align__(16) _Float16 lsVT[64 * SSTR];
    __shared__ __align__(16) _Float16 lsP [64 * PSTR];

    int bid = blockIdx.x;
    int qt  = bid & 31;
    int bh  = bid >> 5;
    int q0  = qt << 6;
    int k0  = q0 - 64;
    int tid = threadIdx.x;
    int lane = tid & 63;
    int w = tid >> 6;
    int l15 = lane & 15, lg = lane >> 4;

    const _Float16* Qb = qh + (long)bh * SDIM * HD;
    const _Float16* Kb = kh + (long)bh * SDIM * HD;
    const _Float16* Vb = vh + (long)bh * SDIM * HD;

    // ---- stage V^T into LDS: wave w covers d in [w*16, w*16+16) ----
#pragma unroll
    for (int c = 0; c < 3; ++c) {
        int rk = c * 64 + lane;
        int s  = k0 + rk;
        s = s < 0 ? 0 : (s >= SDIM ? SDIM - 1 : s);
        const f16x8* vr = (const f16x8*)(Vb + (long)s * HD + w * 16);
        f16x8 v0 = vr[0], v1 = vr[1];
#pragma unroll
        for (int e = 0; e < 8; ++e) {
            lsVT[(w * 16 + e)     * SSTR + rk] = v0[e];
            lsVT[(w * 16 + 8 + e) * SSTR + rk] = v1[e];
        }
    }

    // ---- Q fragments (A-operand: row=l15, k=lg*8+e) ----
    int qrow = q0 + w * 16 + l15;
    const f16x8* qp = (const f16x8*)(Qb + (long)qrow * HD + lg * 8);
    f16x8 qa0 = qp[0];
    f16x8 qa1 = qp[4];   // +32 f16

    // ---- QK^T, mask, exp, P->LDS ----
    float sums[4] = {0.f, 0.f, 0.f, 0.f};
    int iqb = w * 16 + lg * 4;   // query offset (from q0) of this lane's D rows
#pragma unroll 4
    for (int kt = 0; kt < 12; ++kt) {
        int krow = k0 + kt * 16 + l15;
        int kcl = krow < 0 ? 0 : (krow >= SDIM ? SDIM - 1 : krow);
        const f16x8* kp = (const f16x8*)(Kb + (long)kcl * HD + lg * 8);
        f16x8 kb0 = kp[0], kb1 = kp[4];
        f32x4 acc = {0.f, 0.f, 0.f, 0.f};
        acc = __builtin_amdgcn_mfma_f32_16x16x32_f16(qa0, kb0, acc, 0, 0, 0);
        acc = __builtin_amdgcn_mfma_f32_16x16x32_f16(qa1, kb1, acc, 0, 0, 0);
        int jk = kt * 16 + l15;              // key offset (from k0) of D col
        bool kin = (krow >= 0) && (krow < SDIM);
#pragma unroll
        for (int j = 0; j < 4; ++j) {
            int i = iqb + j;
            bool valid = kin && (jk >= i) && (jk <= i + 128);
            float p = valid ? __expf(acc[j] * 0.125f) : 0.f;
            sums[j] += p;
            lsP[(w * 16 + lg * 4 + j) * PSTR + jk] = (_Float16)p;
        }
    }

    // ---- row-sums: reduce across the 16 lanes of each lg group ----
#pragma unroll
    for (int m = 1; m < 16; m <<= 1) {
#pragma unroll
        for (int j = 0; j < 4; ++j)
            sums[j] += __shfl_xor(sums[j], m, 64);
    }
    float inv[4];
#pragma unroll
    for (int j = 0; j < 4; ++j) inv[j] = 1.f / sums[j];

    __syncthreads();   // lsVT staged (cross-wave); lsP is intra-wave

    // ---- PV: A=P[q=l15, k=lg*8+e], B=V^T -> lane B[k, d=l15] ----
    f32x4 accy[4] = {};
    const _Float16* prow = &lsP[(w * 16 + l15) * PSTR + lg * 8];
#pragma unroll
    for (int kc = 0; kc < 6; ++kc) {
        f16x8 pa = *(const f16x8*)(prow + kc * 32);
#pragma unroll
        for (int dt = 0; dt < 4; ++dt) {
            f16x8 vb = *(const f16x8*)&lsVT[(dt * 16 + l15) * SSTR + kc * 32 + lg * 8];
            accy[dt] = __builtin_amdgcn_mfma_f32_16x16x32_f16(pa, vb, accy[dt], 0, 0, 0);
        }
    }

    // ---- epilogue: y*inv -> yh[b, s, h*64+d] f16 ----
    int b = bh / NH, h = bh - (bh / NH) * NH;
    long outbase = ((long)b * SDIM) * HDIM + (long)h * HD;
#pragma unroll
    for (int dt = 0; dt < 4; ++dt) {
#pragma unroll
        for (int j = 0; j < 4; ++j) {
            int srow = q0 + w * 16 + lg * 4 + j;
            yh[outbase + (long)srow * HDIM + dt * 16 + l15] =
                (_Float16)(accy[dt][j] * inv[j]);
        }
    }
}

// ---------------------------------------------------------------------------
extern "C" void kernel_launch(void* const* d_in, const int* in_sizes, int n_in,
                              void* d_out, int out_size, void* d_ws, size_t ws_size,
                              hipStream_t stream)
{
    const float* x    = (const float*)d_in[0];
    const float* cosp = (const float*)d_in[1];
    const float* sinp = (const float*)d_in[2];
    const float* Wqkv = (const float*)d_in[3];
    const float* Wo   = (const float*)d_in[4];
    float* out = (float*)d_out;

    char* ws = (char*)d_ws;
    _Float16* xh    = (_Float16*)(ws);                    // 12,582,912
    _Float16* wqkvh = (_Float16*)(ws + 12582912);         //  3,538,944
    _Float16* woh   = (_Float16*)(ws + 16121856);         //  1,179,648
    _Float16* qh    = (_Float16*)(ws + 17301504);         // 12,582,912
    _Float16* kh    = (_Float16*)(ws + 29884416);         // 12,582,912
    _Float16* vh    = (_Float16*)(ws + 42467328);         // 12,582,912
    _Float16* yh    = (_Float16*)(ws + 55050240);         // 12,582,912 -> 67,633,152 total

    // 1) convert inputs to fp16
    cvt_f32_f16<<<(MROWS * HDIM / 8 + 255) / 256, 256, 0, stream>>>(x, xh, MROWS * HDIM / 8);
    cvt_f32_f16<<<(NQKV * HDIM / 8 + 255) / 256, 256, 0, stream>>>(Wqkv, wqkvh, NQKV * HDIM / 8);
    cvt_f32_f16<<<(HDIM * HDIM / 8 + 255) / 256, 256, 0, stream>>>(Wo, woh, HDIM * HDIM / 8);

    // 2) QKV gemm with fused RoPE + scatter epilogue
    {
        dim3 grid((MROWS / 128) * (NQKV / 128));   // 1152
        gemm_kernel<1><<<grid, 256, 0, stream>>>(
            xh, wqkvh, nullptr, cosp, sinp, qh, kh, vh, MROWS, NQKV, HDIM);
    }

    // 3) sliding-window MFMA attention
    {
        dim3 grid(BDIM * NH * (SDIM / 64));        // 1536
        attn_mfma<<<grid, 256, 0, stream>>>(qh, kh, vh, yh);
    }

    // 4) output projection
    {
        dim3 grid((MROWS / 128) * (HDIM / 128));   // 384
        gemm_kernel<0><<<grid, 256, 0, stream>>>(
            yh, woh, out, nullptr, nullptr, nullptr, nullptr, nullptr,
            MROWS, HDIM, HDIM);
    }
}

// Round 4
// 118.130 us; speedup vs baseline: 1.0330x; 1.0330x over previous
//
#include <hip/hip_runtime.h>

// ---------------------------------------------------------------------------
// ModernBertAttention: x[4,2048,768] -> QKV gemm(+RoPE) -> sliding-window
// MFMA attention (window=64) -> out-proj gemm.  out f32 [4,2048,768].
// ---------------------------------------------------------------------------

typedef __attribute__((ext_vector_type(8))) _Float16 f16x8;
typedef __attribute__((ext_vector_type(4))) float    f32x4;

#define BDIM 4
#define SDIM 2048
#define HDIM 768
#define NH   12
#define HD   64
#define NQKV 2304   // 3*HDIM
#define MROWS 8192  // B*S

// ---------------------------------------------------------------------------
__device__ __forceinline__ void gload16(const void* g, void* l) {
    __builtin_amdgcn_global_load_lds(
        (__attribute__((address_space(1))) void*)(g),
        (__attribute__((address_space(3))) void*)(l),
        16, 0, 0);
}

// --------------------------- f32 -> f16 convert ----------------------------
__global__ __launch_bounds__(256) void cvt_f32_f16(
    const float* __restrict__ src, _Float16* __restrict__ dst, int n8)
{
    int i = blockIdx.x * 256 + threadIdx.x;
    if (i >= n8) return;
    const float4* s4 = (const float4*)src + (long)i * 2;
    float4 a = s4[0], b = s4[1];
    f16x8 o;
    o[0] = (_Float16)a.x; o[1] = (_Float16)a.y;
    o[2] = (_Float16)a.z; o[3] = (_Float16)a.w;
    o[4] = (_Float16)b.x; o[5] = (_Float16)b.y;
    o[6] = (_Float16)b.z; o[7] = (_Float16)b.w;
    *((f16x8*)dst + i) = o;
}

// ------------------------------- GEMM --------------------------------------
// C[M,N] = A[M,K] * Bt[N,K]^T, fp16 inputs, fp32 accum.
// T3 minimum 2-phase pipeline: double-buffered LDS; per k-step issue the
// NEXT tile's global_load_lds first, compute current tile, then one
// __syncthreads() (vmcnt(0)+lgkmcnt(0)+barrier) -- the load latency hides
// under the 16 MFMAs instead of being fully exposed before them.
// EPI==0: plain f32 C store.
// EPI==1: qkv epilogue: RoPE on q/k, scatter q/k/v (all f16) to [B,nh,S,hd].
template <int EPI>
__global__ __launch_bounds__(256) void gemm_kernel(
    const _Float16* __restrict__ A,
    const _Float16* __restrict__ Bt,
    float* __restrict__ C,
    const float* __restrict__ cosp,
    const float* __restrict__ sinp,
    _Float16* __restrict__ qh,
    _Float16* __restrict__ kh,
    _Float16* __restrict__ vh,
    int M, int N, int K)
{
    __shared__ __align__(16) _Float16 lsA[2][128 * 32];
    __shared__ __align__(16) _Float16 lsB[2][128 * 32];

    int nTn = N >> 7;
    int nwg = gridDim.x;
    int bid = blockIdx.x;
    int wg = bid;
    if ((nwg & 7) == 0) {                 // XCD-aware bijective swizzle
        int cpx = nwg >> 3;
        wg = (bid & 7) * cpx + (bid >> 3);
    }
    int tm = wg / nTn, tn = wg % nTn;
    int m0 = tm << 7, n0 = tn << 7;

    int tid  = threadIdx.x;
    int lane = tid & 63;
    int w    = tid >> 6;
    int wr   = w >> 1, wc = w & 1;
    int l15  = lane & 15, lk = lane >> 4;

    f32x4 acc[4][4] = {};

    // staging: thread tid covers rows {tid>>2, tid>>2 + 64}, col (tid&3)*8
    int srow = tid >> 2;
    int scol = (tid & 3) << 3;
    const _Float16* ga0 = A  + (long)(m0 + srow) * K + scol;
    const _Float16* gb0 = Bt + (long)(n0 + srow) * K + scol;
    const long gstep = (long)64 * K;

    const int NK = K >> 5;

    // prologue: stage k-tile 0 into buffer 0
    {
        gload16(ga0,         &lsA[0][tid * 8]);
        gload16(ga0 + gstep, &lsA[0][tid * 8 + 2048]);
        gload16(gb0,         &lsB[0][tid * 8]);
        gload16(gb0 + gstep, &lsB[0][tid * 8 + 2048]);
    }
    __syncthreads();

    int cur = 0;
    for (int it = 0; it < NK; ++it) {
        if (it + 1 < NK) {                 // issue NEXT tile before compute
            const _Float16* ga = ga0 + (it + 1) * 32;
            const _Float16* gb = gb0 + (it + 1) * 32;
            int nb = cur ^ 1;
            gload16(ga,         &lsA[nb][tid * 8]);
            gload16(ga + gstep, &lsA[nb][tid * 8 + 2048]);
            gload16(gb,         &lsB[nb][tid * 8]);
            gload16(gb + gstep, &lsB[nb][tid * 8 + 2048]);
        }

        f16x8 af[4], bfr[4];
#pragma unroll
        for (int m = 0; m < 4; ++m)
            af[m] = *(const f16x8*)&lsA[cur][(wr * 64 + m * 16 + l15) * 32 + lk * 8];
#pragma unroll
        for (int n = 0; n < 4; ++n)
            bfr[n] = *(const f16x8*)&lsB[cur][(wc * 64 + n * 16 + l15) * 32 + lk * 8];
#pragma unroll
        for (int m = 0; m < 4; ++m)
#pragma unroll
            for (int n = 0; n < 4; ++n)
                acc[m][n] = __builtin_amdgcn_mfma_f32_16x16x32_f16(
                    af[m], bfr[n], acc[m][n], 0, 0, 0);

        __syncthreads();   // drains vmcnt(0): next tile staged; barrier
        cur ^= 1;
    }

    if (EPI == 0) {
#pragma unroll
        for (int m = 0; m < 4; ++m)
#pragma unroll
            for (int n = 0; n < 4; ++n)
#pragma unroll
                for (int j = 0; j < 4; ++j) {
                    int gr = m0 + wr * 64 + m * 16 + lk * 4 + j;
                    int gc = n0 + wc * 64 + n * 16 + l15;
                    C[(long)gr * N + gc] = acc[m][n][j];
                }
    } else {
        int ht = (n0 >> 6) + wc;       // [0,36): t*12 + h
        int t  = ht / NH;
        int h  = ht - t * NH;
        int b  = m0 >> 11;
        long base_bh = ((long)(b * NH + h)) * SDIM;
#pragma unroll
        for (int m = 0; m < 4; ++m) {
#pragma unroll
            for (int j = 0; j < 4; ++j) {
                int gr = m0 + wr * 64 + m * 16 + lk * 4 + j;
                int s  = gr & (SDIM - 1);
                if (t == 2) {
#pragma unroll
                    for (int n = 0; n < 4; ++n) {
                        int d = n * 16 + l15;
                        vh[(base_bh + s) * HD + d] = (_Float16)acc[m][n][j];
                    }
                } else {
                    float vals[4];
#pragma unroll
                    for (int n = 0; n < 4; ++n) vals[n] = acc[m][n][j];
#pragma unroll
                    for (int n = 0; n < 4; ++n) {
                        int d = n * 16 + l15;
                        float cc = cosp[(long)gr * HD + d];
                        float ss = sinp[(long)gr * HD + d];
                        float pv = (n < 2) ? -vals[n + 2] : vals[n - 2];
                        float o  = vals[n] * cc + pv * ss;
                        long oidx = (base_bh + s) * HD + d;
                        if (t == 0) qh[oidx] = (_Float16)o;
                        else        kh[oidx] = (_Float16)o;
                    }
                }
            }
        }
    }
}

// ---------------------------- MFMA attention --------------------------------
// Block = 4 waves = one (b,h, 64-query tile); key window = 192 keys.
// QK^T: A=Q (direct global frags), B=K rows (direct global frags).
// exp+mask in-register; row-sums via 16-lane shfl_xor; P -> LDS f16.
// V staged once per block to LDS transposed f16; PV MFMA from LDS.
#define SSTR 200   // lsVT row stride (f16): 400B, 16B-aligned, conflict-benign
#define PSTR 200   // lsP  row stride (f16)
__global__ __launch_bounds__(256) void attn_mfma(
    const _Float16* __restrict__ qh,
    const _Float16* __restrict__ kh,
    const _Float16* __restrict__ vh,
    _Float16* __restrict__ yh)
{
    __shared__ __align__(16) _Float16 lsVT[64 * SSTR];
    __shared__ __align__(16) _Float16 lsP [64 * PSTR];

    int bid = blockIdx.x;
    int qt  = bid & 31;
    int bh  = bid >> 5;
    int q0  = qt << 6;
    int k0  = q0 - 64;
    int tid = threadIdx.x;
    int lane = tid & 63;
    int w = tid >> 6;
    int l15 = lane & 15, lg = lane >> 4;

    const _Float16* Qb = qh + (long)bh * SDIM * HD;
    const _Float16* Kb = kh + (long)bh * SDIM * HD;
    const _Float16* Vb = vh + (long)bh * SDIM * HD;

    // ---- stage V^T into LDS: wave w covers d in [w*16, w*16+16) ----
#pragma unroll
    for (int c = 0; c < 3; ++c) {
        int rk = c * 64 + lane;
        int s  = k0 + rk;
        s = s < 0 ? 0 : (s >= SDIM ? SDIM - 1 : s);
        const f16x8* vr = (const f16x8*)(Vb + (long)s * HD + w * 16);
        f16x8 v0 = vr[0], v1 = vr[1];
#pragma unroll
        for (int e = 0; e < 8; ++e) {
            lsVT[(w * 16 + e)     * SSTR + rk] = v0[e];
            lsVT[(w * 16 + 8 + e) * SSTR + rk] = v1[e];
        }
    }

    // ---- Q fragments (A-operand: row=l15, k=lg*8+e) ----
    int qrow = q0 + w * 16 + l15;
    const f16x8* qp = (const f16x8*)(Qb + (long)qrow * HD + lg * 8);
    f16x8 qa0 = qp[0];
    f16x8 qa1 = qp[4];   // +32 f16

    // ---- QK^T, mask, exp, P->LDS ----
    float sums[4] = {0.f, 0.f, 0.f, 0.f};
    int iqb = w * 16 + lg * 4;   // query offset (from q0) of this lane's D rows
#pragma unroll 4
    for (int kt = 0; kt < 12; ++kt) {
        int krow = k0 + kt * 16 + l15;
        int kcl = krow < 0 ? 0 : (krow >= SDIM ? SDIM - 1 : krow);
        const f16x8* kp = (const f16x8*)(Kb + (long)kcl * HD + lg * 8);
        f16x8 kb0 = kp[0], kb1 = kp[4];
        f32x4 acc = {0.f, 0.f, 0.f, 0.f};
        acc = __builtin_amdgcn_mfma_f32_16x16x32_f16(qa0, kb0, acc, 0, 0, 0);
        acc = __builtin_amdgcn_mfma_f32_16x16x32_f16(qa1, kb1, acc, 0, 0, 0);
        int jk = kt * 16 + l15;              // key offset (from k0) of D col
        bool kin = (krow >= 0) && (krow < SDIM);
#pragma unroll
        for (int j = 0; j < 4; ++j) {
            int i = iqb + j;
            bool valid = kin && (jk >= i) && (jk <= i + 128);
            float p = valid ? __expf(acc[j] * 0.125f) : 0.f;
            sums[j] += p;
            lsP[(w * 16 + lg * 4 + j) * PSTR + jk] = (_Float16)p;
        }
    }

    // ---- row-sums: reduce across the 16 lanes of each lg group ----
#pragma unroll
    for (int m = 1; m < 16; m <<= 1) {
#pragma unroll
        for (int j = 0; j < 4; ++j)
            sums[j] += __shfl_xor(sums[j], m, 64);
    }
    float inv[4];
#pragma unroll
    for (int j = 0; j < 4; ++j) inv[j] = 1.f / sums[j];

    __syncthreads();   // lsVT staged (cross-wave); lsP is intra-wave

    // ---- PV: A=P[q=l15, k=lg*8+e], B=V^T -> lane B[k, d=l15] ----
    f32x4 accy[4] = {};
    const _Float16* prow = &lsP[(w * 16 + l15) * PSTR + lg * 8];
#pragma unroll
    for (int kc = 0; kc < 6; ++kc) {
        f16x8 pa = *(const f16x8*)(prow + kc * 32);
#pragma unroll
        for (int dt = 0; dt < 4; ++dt) {
            f16x8 vb = *(const f16x8*)&lsVT[(dt * 16 + l15) * SSTR + kc * 32 + lg * 8];
            accy[dt] = __builtin_amdgcn_mfma_f32_16x16x32_f16(pa, vb, accy[dt], 0, 0, 0);
        }
    }

    // ---- epilogue: y*inv -> yh[b, s, h*64+d] f16 ----
    int b = bh / NH, h = bh - (bh / NH) * NH;
    long outbase = ((long)b * SDIM) * HDIM + (long)h * HD;
#pragma unroll
    for (int dt = 0; dt < 4; ++dt) {
#pragma unroll
        for (int j = 0; j < 4; ++j) {
            int srow = q0 + w * 16 + lg * 4 + j;
            yh[outbase + (long)srow * HDIM + dt * 16 + l15] =
                (_Float16)(accy[dt][j] * inv[j]);
        }
    }
}

// ---------------------------------------------------------------------------
extern "C" void kernel_launch(void* const* d_in, const int* in_sizes, int n_in,
                              void* d_out, int out_size, void* d_ws, size_t ws_size,
                              hipStream_t stream)
{
    const float* x    = (const float*)d_in[0];
    const float* cosp = (const float*)d_in[1];
    const float* sinp = (const float*)d_in[2];
    const float* Wqkv = (const float*)d_in[3];
    const float* Wo   = (const float*)d_in[4];
    float* out = (float*)d_out;

    char* ws = (char*)d_ws;
    _Float16* xh    = (_Float16*)(ws);                    // 12,582,912
    _Float16* wqkvh = (_Float16*)(ws + 12582912);         //  3,538,944
    _Float16* woh   = (_Float16*)(ws + 16121856);         //  1,179,648
    _Float16* qh    = (_Float16*)(ws + 17301504);         // 12,582,912
    _Float16* kh    = (_Float16*)(ws + 29884416);         // 12,582,912
    _Float16* vh    = (_Float16*)(ws + 42467328);         // 12,582,912
    _Float16* yh    = (_Float16*)(ws + 55050240);         // 12,582,912 -> 67,633,152 total

    // 1) convert inputs to fp16
    cvt_f32_f16<<<(MROWS * HDIM / 8 + 255) / 256, 256, 0, stream>>>(x, xh, MROWS * HDIM / 8);
    cvt_f32_f16<<<(NQKV * HDIM / 8 + 255) / 256, 256, 0, stream>>>(Wqkv, wqkvh, NQKV * HDIM / 8);
    cvt_f32_f16<<<(HDIM * HDIM / 8 + 255) / 256, 256, 0, stream>>>(Wo, woh, HDIM * HDIM / 8);

    // 2) QKV gemm with fused RoPE + scatter epilogue
    {
        dim3 grid((MROWS / 128) * (NQKV / 128));   // 1152
        gemm_kernel<1><<<grid, 256, 0, stream>>>(
            xh, wqkvh, nullptr, cosp, sinp, qh, kh, vh, MROWS, NQKV, HDIM);
    }

    // 3) sliding-window MFMA attention
    {
        dim3 grid(BDIM * NH * (SDIM / 64));        // 1536
        attn_mfma<<<grid, 256, 0, stream>>>(qh, kh, vh, yh);
    }

    // 4) output projection
    {
        dim3 grid((MROWS / 128) * (HDIM / 128));   // 384
        gemm_kernel<0><<<grid, 256, 0, stream>>>(
            yh, woh, out, nullptr, nullptr, nullptr, nullptr, nullptr,
            MROWS, HDIM, HDIM);
    }
}

// Round 5
// 114.611 us; speedup vs baseline: 1.0647x; 1.0307x over previous
//
#include <hip/hip_runtime.h>

// ---------------------------------------------------------------------------
// ModernBertAttention: x[4,2048,768] -> QKV gemm(+RoPE) -> sliding-window
// MFMA attention (window=64) -> out-proj gemm.  out f32 [4,2048,768].
// ---------------------------------------------------------------------------

typedef __attribute__((ext_vector_type(8))) _Float16 f16x8;
typedef __attribute__((ext_vector_type(4))) float    f32x4;

#define BDIM 4
#define SDIM 2048
#define HDIM 768
#define NH   12
#define HD   64
#define NQKV 2304   // 3*HDIM
#define MROWS 8192  // B*S

// ---------------------------------------------------------------------------
__device__ __forceinline__ void gload16(const void* g, void* l) {
    __builtin_amdgcn_global_load_lds(
        (__attribute__((address_space(1))) void*)(g),
        (__attribute__((address_space(3))) void*)(l),
        16, 0, 0);
}

// --------------------------- f32 -> f16 convert ----------------------------
__global__ __launch_bounds__(256) void cvt_f32_f16(
    const float* __restrict__ src, _Float16* __restrict__ dst, int n8)
{
    int i = blockIdx.x * 256 + threadIdx.x;
    if (i >= n8) return;
    const float4* s4 = (const float4*)src + (long)i * 2;
    float4 a = s4[0], b = s4[1];
    f16x8 o;
    o[0] = (_Float16)a.x; o[1] = (_Float16)a.y;
    o[2] = (_Float16)a.z; o[3] = (_Float16)a.w;
    o[4] = (_Float16)b.x; o[5] = (_Float16)b.y;
    o[6] = (_Float16)b.z; o[7] = (_Float16)b.w;
    *((f16x8*)dst + i) = o;
}

// ------------------------------- GEMM --------------------------------------
// C[M,N] = A[M,K] * Bt[N,K]^T, fp16 inputs, fp32 accum.
// T4 counted-vmcnt pipeline (2 tiles deep, raw s_barrier, NEVER vmcnt(0) in
// steady state):
//   prologue: stage(buf0,t0) stage(buf1,t1)            -> 8 per-wave loads
//   iter it : ds_read buf[cur] ; lgkmcnt(0) ; barrier  (all waves done reading)
//             stage(buf[cur], it+2)                    (overwrite is now safe)
//             16x MFMA
//             vmcnt(4) -> tile it+1 resident, it+2 stays in flight ; barrier
// EPI==0: plain f32 C store.
// EPI==1: qkv epilogue: RoPE on q/k, scatter q/k/v (all f16) to [B,nh,S,hd].
template <int EPI>
__global__ __launch_bounds__(256) void gemm_kernel(
    const _Float16* __restrict__ A,
    const _Float16* __restrict__ Bt,
    float* __restrict__ C,
    const float* __restrict__ cosp,
    const float* __restrict__ sinp,
    _Float16* __restrict__ qh,
    _Float16* __restrict__ kh,
    _Float16* __restrict__ vh,
    int M, int N, int K)
{
    __shared__ __align__(16) _Float16 lsA[2][128 * 32];
    __shared__ __align__(16) _Float16 lsB[2][128 * 32];

    int nTn = N >> 7;
    int nwg = gridDim.x;
    int bid = blockIdx.x;
    int wg = bid;
    if ((nwg & 7) == 0) {                 // XCD-aware bijective swizzle
        int cpx = nwg >> 3;
        wg = (bid & 7) * cpx + (bid >> 3);
    }
    int tm = wg / nTn, tn = wg % nTn;
    int m0 = tm << 7, n0 = tn << 7;

    int tid  = threadIdx.x;
    int lane = tid & 63;
    int w    = tid >> 6;
    int wr   = w >> 1, wc = w & 1;
    int l15  = lane & 15, lk = lane >> 4;

    f32x4 acc[4][4] = {};

    // staging: thread tid covers rows {tid>>2, tid>>2 + 64}, col (tid&3)*8
    int srow = tid >> 2;
    int scol = (tid & 3) << 3;
    const _Float16* ga0 = A  + (long)(m0 + srow) * K + scol;
    const _Float16* gb0 = Bt + (long)(n0 + srow) * K + scol;
    const long gstep = (long)64 * K;
    _Float16* laP[2] = { &lsA[0][tid * 8], &lsA[1][tid * 8] };
    _Float16* lbP[2] = { &lsB[0][tid * 8], &lsB[1][tid * 8] };

    const int NK = K >> 5;   // >= 2 for all call sites (K=768 -> 24)

#define STAGE(buf, t) do {                                   \
        const _Float16* ga_ = ga0 + (t) * 32;                \
        const _Float16* gb_ = gb0 + (t) * 32;                \
        gload16(ga_,         laP[buf]);                      \
        gload16(ga_ + gstep, laP[buf] + 2048);               \
        gload16(gb_,         lbP[buf]);                      \
        gload16(gb_ + gstep, lbP[buf] + 2048);               \
    } while (0)

    // prologue: 2 tiles in flight
    STAGE(0, 0);
    STAGE(1, 1);
    asm volatile("s_waitcnt vmcnt(4)" ::: "memory");   // tile 0 resident
    __builtin_amdgcn_s_barrier();

    int cur = 0;
    for (int it = 0; it < NK; ++it) {
        f16x8 af[4], bfr[4];
#pragma unroll
        for (int m = 0; m < 4; ++m)
            af[m] = *(const f16x8*)&lsA[cur][(wr * 64 + m * 16 + l15) * 32 + lk * 8];
#pragma unroll
        for (int n = 0; n < 4; ++n)
            bfr[n] = *(const f16x8*)&lsB[cur][(wc * 64 + n * 16 + l15) * 32 + lk * 8];

        asm volatile("s_waitcnt lgkmcnt(0)" ::: "memory");  // my reads landed
        __builtin_amdgcn_s_barrier();                       // all waves done reading buf[cur]

        if (it + 2 < NK) STAGE(cur, it + 2);                // overwrite safely

#pragma unroll
        for (int m = 0; m < 4; ++m)
#pragma unroll
            for (int n = 0; n < 4; ++n)
                acc[m][n] = __builtin_amdgcn_mfma_f32_16x16x32_f16(
                    af[m], bfr[n], acc[m][n], 0, 0, 0);

        if (it + 1 < NK) {
            if (it + 2 < NK)
                asm volatile("s_waitcnt vmcnt(4)" ::: "memory"); // tile it+1 resident
            else
                asm volatile("s_waitcnt vmcnt(0)" ::: "memory"); // last tile
            __builtin_amdgcn_s_barrier();
        }
        cur ^= 1;
    }
#undef STAGE

    if (EPI == 0) {
#pragma unroll
        for (int m = 0; m < 4; ++m)
#pragma unroll
            for (int n = 0; n < 4; ++n)
#pragma unroll
                for (int j = 0; j < 4; ++j) {
                    int gr = m0 + wr * 64 + m * 16 + lk * 4 + j;
                    int gc = n0 + wc * 64 + n * 16 + l15;
                    C[(long)gr * N + gc] = acc[m][n][j];
                }
    } else {
        int ht = (n0 >> 6) + wc;       // [0,36): t*12 + h
        int t  = ht / NH;
        int h  = ht - t * NH;
        int b  = m0 >> 11;
        long base_bh = ((long)(b * NH + h)) * SDIM;
#pragma unroll
        for (int m = 0; m < 4; ++m) {
#pragma unroll
            for (int j = 0; j < 4; ++j) {
                int gr = m0 + wr * 64 + m * 16 + lk * 4 + j;
                int s  = gr & (SDIM - 1);
                if (t == 2) {
#pragma unroll
                    for (int n = 0; n < 4; ++n) {
                        int d = n * 16 + l15;
                        vh[(base_bh + s) * HD + d] = (_Float16)acc[m][n][j];
                    }
                } else {
                    float vals[4];
#pragma unroll
                    for (int n = 0; n < 4; ++n) vals[n] = acc[m][n][j];
#pragma unroll
                    for (int n = 0; n < 4; ++n) {
                        int d = n * 16 + l15;
                        float cc = cosp[(long)gr * HD + d];
                        float ss = sinp[(long)gr * HD + d];
                        float pv = (n < 2) ? -vals[n + 2] : vals[n - 2];
                        float o  = vals[n] * cc + pv * ss;
                        long oidx = (base_bh + s) * HD + d;
                        if (t == 0) qh[oidx] = (_Float16)o;
                        else        kh[oidx] = (_Float16)o;
                    }
                }
            }
        }
    }
}

// ---------------------------- MFMA attention --------------------------------
// Block = 4 waves = one (b,h, 64-query tile); key window = 192 keys.
// QK^T: A=Q (direct global frags), B=K rows (direct global frags).
// exp+mask in-register; row-sums via 16-lane shfl_xor; P -> LDS f16.
// V staged once per block to LDS transposed f16; PV MFMA from LDS.
#define SSTR 200   // lsVT row stride (f16): 400B, 16B-aligned, conflict-benign
#define PSTR 200   // lsP  row stride (f16)
__global__ __launch_bounds__(256) void attn_mfma(
    const _Float16* __restrict__ qh,
    const _Float16* __restrict__ kh,
    const _Float16* __restrict__ vh,
    _Float16* __restrict__ yh)
{
    __shared__ __align__(16) _Float16 lsVT[64 * SSTR];
    __shared__ __align__(16) _Float16 lsP [64 * PSTR];

    int bid = blockIdx.x;
    int qt  = bid & 31;
    int bh  = bid >> 5;
    int q0  = qt << 6;
    int k0  = q0 - 64;
    int tid = threadIdx.x;
    int lane = tid & 63;
    int w = tid >> 6;
    int l15 = lane & 15, lg = lane >> 4;

    const _Float16* Qb = qh + (long)bh * SDIM * HD;
    const _Float16* Kb = kh + (long)bh * SDIM * HD;
    const _Float16* Vb = vh + (long)bh * SDIM * HD;

    // ---- stage V^T into LDS: wave w covers d in [w*16, w*16+16) ----
#pragma unroll
    for (int c = 0; c < 3; ++c) {
        int rk = c * 64 + lane;
        int s  = k0 + rk;
        s = s < 0 ? 0 : (s >= SDIM ? SDIM - 1 : s);
        const f16x8* vr = (const f16x8*)(Vb + (long)s * HD + w * 16);
        f16x8 v0 = vr[0], v1 = vr[1];
#pragma unroll
        for (int e = 0; e < 8; ++e) {
            lsVT[(w * 16 + e)     * SSTR + rk] = v0[e];
            lsVT[(w * 16 + 8 + e) * SSTR + rk] = v1[e];
        }
    }

    // ---- Q fragments (A-operand: row=l15, k=lg*8+e) ----
    int qrow = q0 + w * 16 + l15;
    const f16x8* qp = (const f16x8*)(Qb + (long)qrow * HD + lg * 8);
    f16x8 qa0 = qp[0];
    f16x8 qa1 = qp[4];   // +32 f16

    // ---- QK^T, mask, exp, P->LDS ----
    float sums[4] = {0.f, 0.f, 0.f, 0.f};
    int iqb = w * 16 + lg * 4;   // query offset (from q0) of this lane's D rows
#pragma unroll 4
    for (int kt = 0; kt < 12; ++kt) {
        int krow = k0 + kt * 16 + l15;
        int kcl = krow < 0 ? 0 : (krow >= SDIM ? SDIM - 1 : krow);
        const f16x8* kp = (const f16x8*)(Kb + (long)kcl * HD + lg * 8);
        f16x8 kb0 = kp[0], kb1 = kp[4];
        f32x4 acc = {0.f, 0.f, 0.f, 0.f};
        acc = __builtin_amdgcn_mfma_f32_16x16x32_f16(qa0, kb0, acc, 0, 0, 0);
        acc = __builtin_amdgcn_mfma_f32_16x16x32_f16(qa1, kb1, acc, 0, 0, 0);
        int jk = kt * 16 + l15;              // key offset (from k0) of D col
        bool kin = (krow >= 0) && (krow < SDIM);
#pragma unroll
        for (int j = 0; j < 4; ++j) {
            int i = iqb + j;
            bool valid = kin && (jk >= i) && (jk <= i + 128);
            float p = valid ? __expf(acc[j] * 0.125f) : 0.f;
            sums[j] += p;
            lsP[(w * 16 + lg * 4 + j) * PSTR + jk] = (_Float16)p;
        }
    }

    // ---- row-sums: reduce across the 16 lanes of each lg group ----
#pragma unroll
    for (int m = 1; m < 16; m <<= 1) {
#pragma unroll
        for (int j = 0; j < 4; ++j)
            sums[j] += __shfl_xor(sums[j], m, 64);
    }
    float inv[4];
#pragma unroll
    for (int j = 0; j < 4; ++j) inv[j] = 1.f / sums[j];

    __syncthreads();   // lsVT staged (cross-wave); lsP is intra-wave

    // ---- PV: A=P[q=l15, k=lg*8+e], B=V^T -> lane B[k, d=l15] ----
    f32x4 accy[4] = {};
    const _Float16* prow = &lsP[(w * 16 + l15) * PSTR + lg * 8];
#pragma unroll
    for (int kc = 0; kc < 6; ++kc) {
        f16x8 pa = *(const f16x8*)(prow + kc * 32);
#pragma unroll
        for (int dt = 0; dt < 4; ++dt) {
            f16x8 vb = *(const f16x8*)&lsVT[(dt * 16 + l15) * SSTR + kc * 32 + lg * 8];
            accy[dt] = __builtin_amdgcn_mfma_f32_16x16x32_f16(pa, vb, accy[dt], 0, 0, 0);
        }
    }

    // ---- epilogue: y*inv -> yh[b, s, h*64+d] f16 ----
    int b = bh / NH, h = bh - (bh / NH) * NH;
    long outbase = ((long)b * SDIM) * HDIM + (long)h * HD;
#pragma unroll
    for (int dt = 0; dt < 4; ++dt) {
#pragma unroll
        for (int j = 0; j < 4; ++j) {
            int srow = q0 + w * 16 + lg * 4 + j;
            yh[outbase + (long)srow * HDIM + dt * 16 + l15] =
                (_Float16)(accy[dt][j] * inv[j]);
        }
    }
}

// ---------------------------------------------------------------------------
extern "C" void kernel_launch(void* const* d_in, const int* in_sizes, int n_in,
                              void* d_out, int out_size, void* d_ws, size_t ws_size,
                              hipStream_t stream)
{
    const float* x    = (const float*)d_in[0];
    const float* cosp = (const float*)d_in[1];
    const float* sinp = (const float*)d_in[2];
    const float* Wqkv = (const float*)d_in[3];
    const float* Wo   = (const float*)d_in[4];
    float* out = (float*)d_out;

    char* ws = (char*)d_ws;
    _Float16* xh    = (_Float16*)(ws);                    // 12,582,912
    _Float16* wqkvh = (_Float16*)(ws + 12582912);         //  3,538,944
    _Float16* woh   = (_Float16*)(ws + 16121856);         //  1,179,648
    _Float16* qh    = (_Float16*)(ws + 17301504);         // 12,582,912
    _Float16* kh    = (_Float16*)(ws + 29884416);         // 12,582,912
    _Float16* vh    = (_Float16*)(ws + 42467328);         // 12,582,912
    _Float16* yh    = (_Float16*)(ws + 55050240);         // 12,582,912 -> 67,633,152 total

    // 1) convert inputs to fp16
    cvt_f32_f16<<<(MROWS * HDIM / 8 + 255) / 256, 256, 0, stream>>>(x, xh, MROWS * HDIM / 8);
    cvt_f32_f16<<<(NQKV * HDIM / 8 + 255) / 256, 256, 0, stream>>>(Wqkv, wqkvh, NQKV * HDIM / 8);
    cvt_f32_f16<<<(HDIM * HDIM / 8 + 255) / 256, 256, 0, stream>>>(Wo, woh, HDIM * HDIM / 8);

    // 2) QKV gemm with fused RoPE + scatter epilogue
    {
        dim3 grid((MROWS / 128) * (NQKV / 128));   // 1152
        gemm_kernel<1><<<grid, 256, 0, stream>>>(
            xh, wqkvh, nullptr, cosp, sinp, qh, kh, vh, MROWS, NQKV, HDIM);
    }

    // 3) sliding-window MFMA attention
    {
        dim3 grid(BDIM * NH * (SDIM / 64));        // 1536
        attn_mfma<<<grid, 256, 0, stream>>>(qh, kh, vh, yh);
    }

    // 4) output projection
    {
        dim3 grid((MROWS / 128) * (HDIM / 128));   // 384
        gemm_kernel<0><<<grid, 256, 0, stream>>>(
            yh, woh, out, nullptr, nullptr, nullptr, nullptr, nullptr,
            MROWS, HDIM, HDIM);
    }
}